// Round 2
// baseline (697.094 us; speedup 1.0000x reference)
//
#include <hip/hip_runtime.h>

#define BATCH   65536
#define IN_DIM  784
#define HDIM    20
#define NCLS    10

#define THREADS 256
#define SPB     256            // samples per block (1 per thread)
#define KC      32             // k-chunk per tile
#define NFULL   24             // 24 full tiles of 32
#define KTAIL   16             // 784 = 24*32 + 16
#define TSTRIDE 257            // LDS row stride (floats): reads conflict-free

// sorted(set(row))[:2] -> (e0, e1, mask). mask=0 when only one unique module.
__device__ __forceinline__ void route(const int* pw, bool is64, int row,
                                      int& e0, int& e1, float& m) {
    int v0, v1, v2;
    if (is64) {
        v0 = pw[(row * 3 + 0) * 2];
        v1 = pw[(row * 3 + 1) * 2];
        v2 = pw[(row * 3 + 2) * 2];
    } else {
        v0 = pw[row * 3 + 0];
        v1 = pw[row * 3 + 1];
        v2 = pw[row * 3 + 2];
    }
    int lo  = min(v0, min(v1, v2));
    int hi  = max(v0, max(v1, v2));
    int mid = v0 + v1 + v2 - lo - hi;
    e0 = lo;
    if (mid != lo)     { e1 = mid; m = 1.0f; }
    else if (hi != lo) { e1 = hi;  m = 1.0f; }
    else               { e1 = lo;  m = 0.0f; }
}

// ---- staging: tile i covers k in [kb, kb+32); LDS layout tT[kk][s], stride 257
__device__ __forceinline__ void load32(const float* __restrict__ xg, int kb,
                                       int u, float4 st[8]) {
#pragma unroll
    for (int p = 0; p < 8; ++p) {
        const int s  = p * 32 + (u >> 3);
        const int c4 = u & 7;
        st[p] = *reinterpret_cast<const float4*>(xg + (size_t)s * IN_DIM + kb + c4 * 4);
    }
}
__device__ __forceinline__ void write32(float* __restrict__ tT, int u,
                                        const float4 st[8]) {
#pragma unroll
    for (int p = 0; p < 8; ++p) {
        const int s  = p * 32 + (u >> 3);
        const int c4 = u & 7;
        tT[(c4 * 4 + 0) * TSTRIDE + s] = st[p].x;
        tT[(c4 * 4 + 1) * TSTRIDE + s] = st[p].y;
        tT[(c4 * 4 + 2) * TSTRIDE + s] = st[p].z;
        tT[(c4 * 4 + 3) * TSTRIDE + s] = st[p].w;
    }
}
__device__ __forceinline__ void load16(const float* __restrict__ xg, int kb,
                                       int u, float4 st[8]) {
#pragma unroll
    for (int p = 0; p < 4; ++p) {
        const int s  = p * 64 + (u >> 2);
        const int c4 = u & 3;
        st[p] = *reinterpret_cast<const float4*>(xg + (size_t)s * IN_DIM + kb + c4 * 4);
    }
}
__device__ __forceinline__ void write16(float* __restrict__ tT, int u,
                                        const float4 st[8]) {
#pragma unroll
    for (int p = 0; p < 4; ++p) {
        const int s  = p * 64 + (u >> 2);
        const int c4 = u & 3;
        tT[(c4 * 4 + 0) * TSTRIDE + s] = st[p].x;
        tT[(c4 * 4 + 1) * TSTRIDE + s] = st[p].y;
        tT[(c4 * 4 + 2) * TSTRIDE + s] = st[p].z;
        tT[(c4 * 4 + 3) * TSTRIDE + s] = st[p].w;
    }
}

// ---- compute: acc[o] += sum_kk x[kk] * W[o][kb+kk], 2 experts, scalar weights
template<int KK>
__device__ __forceinline__ void compute_tile(const float* __restrict__ tT, int t,
                                             const float* __restrict__ w0k,
                                             const float* __restrict__ w1k,
                                             float* acc0, float* acc1) {
    float xv[KK];
#pragma unroll
    for (int kk = 0; kk < KK; ++kk) xv[kk] = tT[kk * TSTRIDE + t];
#pragma unroll
    for (int o = 0; o < HDIM; ++o) {
        const float* r0 = w0k + o * IN_DIM;
        const float* r1 = w1k + o * IN_DIM;
        float a0 = 0.0f, a1 = 0.0f;
#pragma unroll
        for (int kk = 0; kk < KK; ++kk) {
            a0 += xv[kk] * r0[kk];
            a1 += xv[kk] * r1[kk];
        }
        acc0[o] += a0;
        acc1[o] += a1;
    }
}

__global__ __launch_bounds__(THREADS, 1)
void pathnet_kernel(const float* __restrict__ x,
                    const float* __restrict__ W1, const float* __restrict__ b1,
                    const float* __restrict__ W2, const float* __restrict__ b2,
                    const float* __restrict__ W3, const float* __restrict__ b3,
                    const float* __restrict__ Wl, const float* __restrict__ bl,
                    const int*   __restrict__ pathway,
                    float* __restrict__ out)
{
    __shared__ float tT[2][KC * TSTRIDE];   // 2 x 32.9 KB double buffer

    const int t = threadIdx.x;

    // ---- routing (uniform) ----
    bool is64 = ((pathway[1] | pathway[3] | pathway[5] | pathway[7]) == 0);
    int e10, e11, e20, e21, e30, e31;
    float m1, m2, m3;
    route(pathway, is64, 0, e10, e11, m1);
    route(pathway, is64, 1, e20, e21, m2);
    route(pathway, is64, 2, e30, e31, m3);
    e10 = __builtin_amdgcn_readfirstlane(e10);
    e11 = __builtin_amdgcn_readfirstlane(e11);
    e20 = __builtin_amdgcn_readfirstlane(e20);
    e21 = __builtin_amdgcn_readfirstlane(e21);
    e30 = __builtin_amdgcn_readfirstlane(e30);
    e31 = __builtin_amdgcn_readfirstlane(e31);

    const size_t s0 = (size_t)blockIdx.x * SPB;
    const float* xg = x + s0 * IN_DIM;
    const float* w0 = W1 + (size_t)e10 * HDIM * IN_DIM;
    const float* w1 = W1 + (size_t)e11 * HDIM * IN_DIM;

    // ---- prologue: stage tile 0 ----
    float4 st[8];
    load32(xg, 0, t, st);
    write32(tT[0], t, st);
    __syncthreads();

    float acc0[HDIM], acc1[HDIM];
#pragma unroll
    for (int o = 0; o < HDIM; ++o) { acc0[o] = 0.0f; acc1[o] = 0.0f; }

    // ---- layer-1 main loop: prefetch i+1 to regs, compute i, write i+1 ----
    for (int i = 0; i < NFULL; ++i) {
        if (i < NFULL - 1) load32(xg, (i + 1) * KC, t, st);
        else               load16(xg, NFULL * KC, t, st);
        compute_tile<KC>(tT[i & 1], t, w0 + i * KC, w1 + i * KC, acc0, acc1);
        if (i < NFULL - 1) write32(tT[(i + 1) & 1], t, st);
        else               write16(tT[(i + 1) & 1], t, st);
        __syncthreads();
    }
    compute_tile<KTAIL>(tT[NFULL & 1], t, w0 + NFULL * KC, w1 + NFULL * KC,
                        acc0, acc1);

    // ---- h1 in registers ----
    float h1[HDIM];
#pragma unroll
    for (int o = 0; o < HDIM; ++o)
        h1[o] = fmaxf(acc0[o] + b1[e10 * HDIM + o], 0.0f)
              + m1 * fmaxf(acc1[o] + b1[e11 * HDIM + o], 0.0f);

    // ---- layer 2 (all scalar weights, per-thread) ----
    float h2[HDIM];
#pragma unroll
    for (int o = 0; o < HDIM; ++o) {
        float a0 = b2[e20 * HDIM + o];
        float a1 = b2[e21 * HDIM + o];
#pragma unroll
        for (int c = 0; c < HDIM; ++c) {
            a0 += h1[c] * W2[((size_t)e20 * HDIM + o) * HDIM + c];
            a1 += h1[c] * W2[((size_t)e21 * HDIM + o) * HDIM + c];
        }
        h2[o] = fmaxf(a0, 0.0f) + m2 * fmaxf(a1, 0.0f);
    }

    // ---- layer 3 ----
    float h3[HDIM];
#pragma unroll
    for (int o = 0; o < HDIM; ++o) {
        float a0 = b3[e30 * HDIM + o];
        float a1 = b3[e31 * HDIM + o];
#pragma unroll
        for (int c = 0; c < HDIM; ++c) {
            a0 += h2[c] * W3[((size_t)e30 * HDIM + o) * HDIM + c];
            a1 += h2[c] * W3[((size_t)e31 * HDIM + o) * HDIM + c];
        }
        h3[o] = fmaxf(a0, 0.0f) + m3 * fmaxf(a1, 0.0f);
    }

    // ---- readout + store (float2, 8B aligned since 10 floats = 40 B) ----
    float y[NCLS];
#pragma unroll
    for (int c = 0; c < NCLS; ++c) {
        float v = bl[c];
#pragma unroll
        for (int o = 0; o < HDIM; ++o)
            v += h3[o] * Wl[c * HDIM + o];
        y[c] = v;
    }
    float* op = out + (s0 + t) * NCLS;
#pragma unroll
    for (int j = 0; j < 5; ++j)
        *reinterpret_cast<float2*>(op + 2 * j) = make_float2(y[2 * j], y[2 * j + 1]);
}

extern "C" void kernel_launch(void* const* d_in, const int* in_sizes, int n_in,
                              void* d_out, int out_size, void* d_ws, size_t ws_size,
                              hipStream_t stream) {
    const float* x  = (const float*)d_in[0];
    const float* W1 = (const float*)d_in[1];
    const float* b1 = (const float*)d_in[2];
    const float* W2 = (const float*)d_in[3];
    const float* b2 = (const float*)d_in[4];
    const float* W3 = (const float*)d_in[5];
    const float* b3 = (const float*)d_in[6];
    const float* Wl = (const float*)d_in[7];
    const float* bl = (const float*)d_in[8];
    const int*   pw = (const int*)d_in[9];
    float* out = (float*)d_out;

    dim3 grid(BATCH / SPB);   // 256 blocks, 1 per CU
    pathnet_kernel<<<grid, THREADS, 0, stream>>>(x, W1, b1, W2, b2,
                                                 W3, b3, Wl, bl, pw, out);
}

// Round 3
// 303.542 us; speedup vs baseline: 2.2965x; 2.2965x over previous
//
#include <hip/hip_runtime.h>

#define BATCH   65536
#define IN_DIM  784
#define HDIM    20
#define NCLS    10

#define THREADS 256
#define SPB     64             // samples per block (4 lanes per sample)
#define NIT     49             // 784 = 49 * 16, no tail

// sorted(set(row))[:2] -> (e0, e1, mask). mask=0 when only one unique module.
__device__ __forceinline__ void route(const int* pw, bool is64, int row,
                                      int& e0, int& e1, float& m) {
    int v0, v1, v2;
    if (is64) {
        v0 = pw[(row * 3 + 0) * 2];
        v1 = pw[(row * 3 + 1) * 2];
        v2 = pw[(row * 3 + 2) * 2];
    } else {
        v0 = pw[row * 3 + 0];
        v1 = pw[row * 3 + 1];
        v2 = pw[row * 3 + 2];
    }
    int lo  = min(v0, min(v1, v2));
    int hi  = max(v0, max(v1, v2));
    int mid = v0 + v1 + v2 - lo - hi;
    e0 = lo;
    if (mid != lo)     { e1 = mid; m = 1.0f; }
    else if (hi != lo) { e1 = hi;  m = 1.0f; }
    else               { e1 = lo;  m = 0.0f; }
}

// Gather the 4 per-lane 5-slices into a full canonical 20-vector, static idx.
__device__ __forceinline__ void gather20(const float my5[5], int ksub,
                                         float outv[HDIM]) {
    float r1[5];
#pragma unroll
    for (int j = 0; j < 5; ++j) r1[j] = __shfl_xor(my5[j], 1, 64);
    const bool b0 = (ksub & 1);
    float q[10];
#pragma unroll
    for (int j = 0; j < 5; ++j) {
        q[j]     = b0 ? r1[j]  : my5[j];   // lo slice of my pair
        q[5 + j] = b0 ? my5[j] : r1[j];    // hi slice of my pair
    }
    float r2[10];
#pragma unroll
    for (int j = 0; j < 10; ++j) r2[j] = __shfl_xor(q[j], 2, 64);
    const bool b1 = (ksub & 2);
#pragma unroll
    for (int j = 0; j < 10; ++j) {
        outv[j]      = b1 ? r2[j] : q[j];
        outv[10 + j] = b1 ? q[j]  : r2[j];
    }
}

__global__ __launch_bounds__(THREADS, 3)
void pathnet_kernel(const float* __restrict__ x,
                    const float* __restrict__ W1, const float* __restrict__ b1,
                    const float* __restrict__ W2, const float* __restrict__ b2,
                    const float* __restrict__ W3, const float* __restrict__ b3,
                    const float* __restrict__ Wl, const float* __restrict__ bl,
                    const int*   __restrict__ pathway,
                    float* __restrict__ out)
{
    const int t    = threadIdx.x;
    const int ksub = t & 3;                       // k-quarter within sample
    const int srow = blockIdx.x * SPB + (t >> 2); // global sample

    // ---- routing (uniform) ----
    bool is64 = ((pathway[1] | pathway[3] | pathway[5] | pathway[7]) == 0);
    int e10, e11, e20, e21, e30, e31;
    float m1, m2, m3;
    route(pathway, is64, 0, e10, e11, m1);
    route(pathway, is64, 1, e20, e21, m2);
    route(pathway, is64, 2, e30, e31, m3);
    e10 = __builtin_amdgcn_readfirstlane(e10);
    e11 = __builtin_amdgcn_readfirstlane(e11);
    e20 = __builtin_amdgcn_readfirstlane(e20);
    e21 = __builtin_amdgcn_readfirstlane(e21);
    e30 = __builtin_amdgcn_readfirstlane(e30);
    e31 = __builtin_amdgcn_readfirstlane(e31);

    // ---- layer 1: lane ksub covers k = i*16 + ksub*4 + {0..3} ----
    float acc[2 * HDIM];
#pragma unroll
    for (int o = 0; o < 2 * HDIM; ++o) acc[o] = 0.0f;

    const float* w0 = W1 + (size_t)e10 * HDIM * IN_DIM;
    const float* w1 = W1 + (size_t)e11 * HDIM * IN_DIM;
    const float* xp = x + (size_t)srow * IN_DIM + ksub * 4;

    for (int i = 0; i < NIT; ++i) {
        const float4 xv = *reinterpret_cast<const float4*>(xp + i * 16);
        const int k = i * 16 + ksub * 4;
#pragma unroll
        for (int o = 0; o < HDIM; ++o) {
            const float4 a = *reinterpret_cast<const float4*>(w0 + o * IN_DIM + k);
            const float4 b = *reinterpret_cast<const float4*>(w1 + o * IN_DIM + k);
            acc[o]        += xv.x * a.x + xv.y * a.y + xv.z * a.z + xv.w * a.w;
            acc[HDIM + o] += xv.x * b.x + xv.y * b.y + xv.z * b.z + xv.w * b.w;
        }
    }

    // ---- butterfly over the 4 k-lanes ----
#pragma unroll
    for (int o = 0; o < 2 * HDIM; ++o) {
        acc[o] += __shfl_xor(acc[o], 1, 64);
        acc[o] += __shfl_xor(acc[o], 2, 64);
    }

    // ---- h1 (all lanes, full) ----
    float h1[HDIM];
#pragma unroll
    for (int o = 0; o < HDIM; ++o)
        h1[o] = fmaxf(acc[o] + b1[e10 * HDIM + o], 0.0f)
              + m1 * fmaxf(acc[HDIM + o] + b1[e11 * HDIM + o], 0.0f);

    // ---- layer 2: lane computes outputs [ksub*5, ksub*5+5), then gather ----
    float my5[5];
#pragma unroll
    for (int j = 0; j < 5; ++j) {
        const int o = ksub * 5 + j;
        float a0 = b2[e20 * HDIM + o];
        float a1 = b2[e21 * HDIM + o];
        const float* r0 = W2 + ((size_t)e20 * HDIM + o) * HDIM;
        const float* r1 = W2 + ((size_t)e21 * HDIM + o) * HDIM;
#pragma unroll
        for (int c = 0; c < HDIM; ++c) {
            a0 += h1[c] * r0[c];
            a1 += h1[c] * r1[c];
        }
        my5[j] = fmaxf(a0, 0.0f) + m2 * fmaxf(a1, 0.0f);
    }
    float h2[HDIM];
    gather20(my5, ksub, h2);

    // ---- layer 3 ----
#pragma unroll
    for (int j = 0; j < 5; ++j) {
        const int o = ksub * 5 + j;
        float a0 = b3[e30 * HDIM + o];
        float a1 = b3[e31 * HDIM + o];
        const float* r0 = W3 + ((size_t)e30 * HDIM + o) * HDIM;
        const float* r1 = W3 + ((size_t)e31 * HDIM + o) * HDIM;
#pragma unroll
        for (int c = 0; c < HDIM; ++c) {
            a0 += h2[c] * r0[c];
            a1 += h2[c] * r1[c];
        }
        my5[j] = fmaxf(a0, 0.0f) + m3 * fmaxf(a1, 0.0f);
    }
    float h3[HDIM];
    gather20(my5, ksub, h3);

    // ---- readout: lane computes its own 2 classes (+8,9 on ksub==0) ----
    const int c0 = ksub * 2;
    float ya = bl[c0], yb = bl[c0 + 1];
    const float* wr0 = Wl + c0 * HDIM;
    const float* wr1 = Wl + (c0 + 1) * HDIM;
#pragma unroll
    for (int o = 0; o < HDIM; ++o) {
        ya += h3[o] * wr0[o];
        yb += h3[o] * wr1[o];
    }
    float* op = out + (size_t)srow * NCLS;
    *reinterpret_cast<float2*>(op + c0) = make_float2(ya, yb);

    if (ksub == 0) {
        float y8 = bl[8], y9 = bl[9];
        const float* w8 = Wl + 8 * HDIM;
        const float* w9 = Wl + 9 * HDIM;
#pragma unroll
        for (int o = 0; o < HDIM; ++o) {
            y8 += h3[o] * w8[o];
            y9 += h3[o] * w9[o];
        }
        *reinterpret_cast<float2*>(op + 8) = make_float2(y8, y9);
    }
}

extern "C" void kernel_launch(void* const* d_in, const int* in_sizes, int n_in,
                              void* d_out, int out_size, void* d_ws, size_t ws_size,
                              hipStream_t stream) {
    const float* x  = (const float*)d_in[0];
    const float* W1 = (const float*)d_in[1];
    const float* b1 = (const float*)d_in[2];
    const float* W2 = (const float*)d_in[3];
    const float* b2 = (const float*)d_in[4];
    const float* W3 = (const float*)d_in[5];
    const float* b3 = (const float*)d_in[6];
    const float* Wl = (const float*)d_in[7];
    const float* bl = (const float*)d_in[8];
    const int*   pw = (const int*)d_in[9];
    float* out = (float*)d_out;

    dim3 grid(BATCH / SPB);   // 1024 blocks, no LDS, no barriers
    pathnet_kernel<<<grid, THREADS, 0, stream>>>(x, W1, b1, W2, b2,
                                                 W3, b3, Wl, bl, pw, out);
}

// Round 4
// 92.002 us; speedup vs baseline: 7.5769x; 3.2993x over previous
//
#include <hip/hip_runtime.h>

#define BATCH   65536
#define IN_DIM  784
#define HDIM    20
#define NCLS    10
#define THREADS 256
#define SPW     16            // samples per wave (MFMA M)
#define SPB     64            // samples per block (4 waves)
#define NSTEP   24            // full K-steps of 32; tail 16
#define PSTRIDE 49            // LDS pre-act row stride (conflict-free)

typedef __attribute__((ext_vector_type(8))) short bf16x8;
typedef __attribute__((ext_vector_type(4))) float f32x4;

typedef union { unsigned u[4]; bf16x8 v; } Frag;

// sorted(set(row))[:2] -> (e0, e1, mask). mask=0 when only one unique module.
__device__ __forceinline__ void route(const int* pw, bool is64, int row,
                                      int& e0, int& e1, float& m) {
    int v0, v1, v2;
    if (is64) {
        v0 = pw[(row * 3 + 0) * 2];
        v1 = pw[(row * 3 + 1) * 2];
        v2 = pw[(row * 3 + 2) * 2];
    } else {
        v0 = pw[row * 3 + 0];
        v1 = pw[row * 3 + 1];
        v2 = pw[row * 3 + 2];
    }
    int lo  = min(v0, min(v1, v2));
    int hi  = max(v0, max(v1, v2));
    int mid = v0 + v1 + v2 - lo - hi;
    e0 = lo;
    if (mid != lo)     { e1 = mid; m = 1.0f; }
    else if (hi != lo) { e1 = hi;  m = 1.0f; }
    else               { e1 = lo;  m = 0.0f; }
}

// packed pair: low16 = bf16-trunc(a), high16 = bf16-trunc(b)
__device__ __forceinline__ unsigned packpair(unsigned a, unsigned b) {
    return (b & 0xffff0000u) | (a >> 16);
}

// 8 fp32 -> hi/lo bf16x8 (truncated split; lo catches the remainder)
__device__ __forceinline__ void cvt8(const unsigned* v, Frag& hi, Frag& lo) {
#pragma unroll
    for (int j = 0; j < 4; ++j) {
        const unsigned a = v[2 * j], b = v[2 * j + 1];
        hi.u[j] = packpair(a, b);
        const float la = __uint_as_float(a) - __uint_as_float(a & 0xffff0000u);
        const float lb = __uint_as_float(b) - __uint_as_float(b & 0xffff0000u);
        lo.u[j] = packpair(__float_as_uint(la), __float_as_uint(lb));
    }
}

__device__ __forceinline__ void ld8(const float* p, unsigned* v) {
    const float4 q0 = *reinterpret_cast<const float4*>(p);
    const float4 q1 = *reinterpret_cast<const float4*>(p + 4);
    v[0] = __float_as_uint(q0.x); v[1] = __float_as_uint(q0.y);
    v[2] = __float_as_uint(q0.z); v[3] = __float_as_uint(q0.w);
    v[4] = __float_as_uint(q1.x); v[5] = __float_as_uint(q1.y);
    v[6] = __float_as_uint(q1.z); v[7] = __float_as_uint(q1.w);
}

// gather the 4 per-lane 5-slices into a full 20-vector (static indexing)
__device__ __forceinline__ void gather20(const float my5[5], int ksub,
                                         float outv[HDIM]) {
    float r1[5];
#pragma unroll
    for (int j = 0; j < 5; ++j) r1[j] = __shfl_xor(my5[j], 1, 64);
    const bool b0 = (ksub & 1);
    float q[10];
#pragma unroll
    for (int j = 0; j < 5; ++j) {
        q[j]     = b0 ? r1[j]  : my5[j];
        q[5 + j] = b0 ? my5[j] : r1[j];
    }
    float r2[10];
#pragma unroll
    for (int j = 0; j < 10; ++j) r2[j] = __shfl_xor(q[j], 2, 64);
    const bool b1 = (ksub & 2);
#pragma unroll
    for (int j = 0; j < 10; ++j) {
        outv[j]      = b1 ? r2[j] : q[j];
        outv[10 + j] = b1 ? q[j]  : r2[j];
    }
}

__global__ __launch_bounds__(THREADS, 4)
void pathnet_kernel(const float* __restrict__ x,
                    const float* __restrict__ W1, const float* __restrict__ b1,
                    const float* __restrict__ W2, const float* __restrict__ b2,
                    const float* __restrict__ W3, const float* __restrict__ b3,
                    const float* __restrict__ Wl, const float* __restrict__ bl,
                    const int*   __restrict__ pathway,
                    float* __restrict__ out)
{
    __shared__ float preLds[4][SPW][PSTRIDE];   // 12.25 KB

    const int t    = threadIdx.x;
    const int lane = t & 63;
    const int w    = __builtin_amdgcn_readfirstlane(t >> 6);

    // ---- routing (uniform) ----
    bool is64 = ((pathway[1] | pathway[3] | pathway[5] | pathway[7]) == 0);
    int e10, e11, e20, e21, e30, e31;
    float m1, m2, m3;
    route(pathway, is64, 0, e10, e11, m1);
    route(pathway, is64, 1, e20, e21, m2);
    route(pathway, is64, 2, e30, e31, m3);
    e10 = __builtin_amdgcn_readfirstlane(e10);
    e11 = __builtin_amdgcn_readfirstlane(e11);
    e20 = __builtin_amdgcn_readfirstlane(e20);
    e21 = __builtin_amdgcn_readfirstlane(e21);
    e30 = __builtin_amdgcn_readfirstlane(e30);
    e31 = __builtin_amdgcn_readfirstlane(e31);

    // ---- layer 1 as MFMA GEMM: C[16 samples][48 units] per wave ----
    const int row = lane & 15;            // A row / B col within tile
    const int kg  = lane >> 4;            // k-group (8 elems each)
    const int sbase = blockIdx.x * SPB + w * SPW;

    const float* aptr = x + (size_t)(sbase + row) * IN_DIM + kg * 8;

    const float* bptr[3];
#pragma unroll
    for (int tt = 0; tt < 3; ++tt) {
        int u = tt * 16 + row;            // unit 0..47
        int e, o;
        if (u < HDIM)          { e = e10; o = u; }
        else if (u < 2 * HDIM) { e = e11; o = u - HDIM; }
        else                   { e = e10; o = 0; }   // pad cols: safe garbage
        bptr[tt] = W1 + ((size_t)e * HDIM + o) * IN_DIM + kg * 8;
    }

    f32x4 acc[3];
#pragma unroll
    for (int tt = 0; tt < 3; ++tt) acc[tt] = (f32x4){0.f, 0.f, 0.f, 0.f};

    for (int i = 0; i < NSTEP; ++i) {
        const int k0 = i * 32;
        unsigned av[8];
        ld8(aptr + k0, av);
        Frag ah, al;
        cvt8(av, ah, al);
#pragma unroll
        for (int tt = 0; tt < 3; ++tt) {
            unsigned bv[8];
            ld8(bptr[tt] + k0, bv);
            Frag bh, bl_;
            cvt8(bv, bh, bl_);
            acc[tt] = __builtin_amdgcn_mfma_f32_16x16x32_bf16(ah.v, bh.v,  acc[tt], 0, 0, 0);
            acc[tt] = __builtin_amdgcn_mfma_f32_16x16x32_bf16(al.v, bh.v,  acc[tt], 0, 0, 0);
            acc[tt] = __builtin_amdgcn_mfma_f32_16x16x32_bf16(ah.v, bl_.v, acc[tt], 0, 0, 0);
        }
    }
    {   // tail: k0 = 768, 16 valid k -> only k-groups 0,1 load; 2,3 are zero
        const int k0 = NSTEP * 32;
        unsigned av[8] = {0, 0, 0, 0, 0, 0, 0, 0};
        if (kg < 2) ld8(aptr + k0, av);
        Frag ah, al;
        cvt8(av, ah, al);
#pragma unroll
        for (int tt = 0; tt < 3; ++tt) {
            unsigned bv[8] = {0, 0, 0, 0, 0, 0, 0, 0};
            if (kg < 2) ld8(bptr[tt] + k0, bv);
            Frag bh, bl_;
            cvt8(bv, bh, bl_);
            acc[tt] = __builtin_amdgcn_mfma_f32_16x16x32_bf16(ah.v, bh.v,  acc[tt], 0, 0, 0);
            acc[tt] = __builtin_amdgcn_mfma_f32_16x16x32_bf16(al.v, bh.v,  acc[tt], 0, 0, 0);
            acc[tt] = __builtin_amdgcn_mfma_f32_16x16x32_bf16(ah.v, bl_.v, acc[tt], 0, 0, 0);
        }
    }

    // ---- C frag -> LDS: col = lane&15 (+16*tile), row = (lane>>4)*4 + reg ----
#pragma unroll
    for (int tt = 0; tt < 3; ++tt) {
        const int col = tt * 16 + row;
        if (col < 2 * HDIM) {
#pragma unroll
            for (int r = 0; r < 4; ++r)
                preLds[w][kg * 4 + r][col] = acc[tt][r];
        }
    }
    __syncthreads();

    // ---- epilogue: 4 lanes per sample (proven round-3 path) ----
    const int s    = lane >> 2;           // local sample 0..15
    const int ksub = lane & 3;

    float h1[HDIM];
#pragma unroll
    for (int c = 0; c < HDIM; ++c) {
        const float p0 = preLds[w][s][c];
        const float p1 = preLds[w][s][HDIM + c];
        h1[c] = fmaxf(p0 + b1[e10 * HDIM + c], 0.0f)
              + m1 * fmaxf(p1 + b1[e11 * HDIM + c], 0.0f);
    }

    float my5[5];
#pragma unroll
    for (int j = 0; j < 5; ++j) {
        const int o = ksub * 5 + j;
        float a0 = b2[e20 * HDIM + o];
        float a1 = b2[e21 * HDIM + o];
        const float* r0 = W2 + ((size_t)e20 * HDIM + o) * HDIM;
        const float* r1 = W2 + ((size_t)e21 * HDIM + o) * HDIM;
#pragma unroll
        for (int c = 0; c < HDIM; ++c) {
            a0 += h1[c] * r0[c];
            a1 += h1[c] * r1[c];
        }
        my5[j] = fmaxf(a0, 0.0f) + m2 * fmaxf(a1, 0.0f);
    }
    float h2[HDIM];
    gather20(my5, ksub, h2);

#pragma unroll
    for (int j = 0; j < 5; ++j) {
        const int o = ksub * 5 + j;
        float a0 = b3[e30 * HDIM + o];
        float a1 = b3[e31 * HDIM + o];
        const float* r0 = W3 + ((size_t)e30 * HDIM + o) * HDIM;
        const float* r1 = W3 + ((size_t)e31 * HDIM + o) * HDIM;
#pragma unroll
        for (int c = 0; c < HDIM; ++c) {
            a0 += h2[c] * r0[c];
            a1 += h2[c] * r1[c];
        }
        my5[j] = fmaxf(a0, 0.0f) + m3 * fmaxf(a1, 0.0f);
    }
    float h3[HDIM];
    gather20(my5, ksub, h3);

    const int srow = sbase + s;
    const int c0 = ksub * 2;
    float ya = bl[c0], yb = bl[c0 + 1];
    const float* wr0 = Wl + c0 * HDIM;
    const float* wr1 = Wl + (c0 + 1) * HDIM;
#pragma unroll
    for (int o = 0; o < HDIM; ++o) {
        ya += h3[o] * wr0[o];
        yb += h3[o] * wr1[o];
    }
    float* op = out + (size_t)srow * NCLS;
    *reinterpret_cast<float2*>(op + c0) = make_float2(ya, yb);

    if (ksub == 0) {
        float y8 = bl[8], y9 = bl[9];
        const float* w8 = Wl + 8 * HDIM;
        const float* w9 = Wl + 9 * HDIM;
#pragma unroll
        for (int o = 0; o < HDIM; ++o) {
            y8 += h3[o] * w8[o];
            y9 += h3[o] * w9[o];
        }
        *reinterpret_cast<float2*>(op + 8) = make_float2(y8, y9);
    }
}

extern "C" void kernel_launch(void* const* d_in, const int* in_sizes, int n_in,
                              void* d_out, int out_size, void* d_ws, size_t ws_size,
                              hipStream_t stream) {
    const float* x  = (const float*)d_in[0];
    const float* W1 = (const float*)d_in[1];
    const float* b1 = (const float*)d_in[2];
    const float* W2 = (const float*)d_in[3];
    const float* b2 = (const float*)d_in[4];
    const float* W3 = (const float*)d_in[5];
    const float* b3 = (const float*)d_in[6];
    const float* Wl = (const float*)d_in[7];
    const float* bl = (const float*)d_in[8];
    const int*   pw = (const int*)d_in[9];
    float* out = (float*)d_out;

    dim3 grid(BATCH / SPB);   // 1024 blocks x 4 waves
    pathnet_kernel<<<grid, THREADS, 0, stream>>>(x, W1, b1, W2, b2,
                                                 W3, b3, Wl, bl, pw, out);
}

// Round 6
// 72.537 us; speedup vs baseline: 9.6101x; 1.2683x over previous
//
#include <hip/hip_runtime.h>

#define BATCH   65536
#define IN_DIM  784
#define HDIM    20
#define NCLS    10
#define THREADS 256
#define SPW     16            // samples per wave (MFMA M)
#define SPB     64            // samples per block (4 waves)
#define NFULL   24            // full K-steps of 32; step 24 = 16-wide tail
#define NSTEPS  25
#define PSTRIDE 49            // LDS pre-act row stride (conflict-free)
#define W1ELEMS (10 * HDIM * IN_DIM)   // 156800

typedef __attribute__((ext_vector_type(2))) __fp16   fp16x2;   // cvt_pkrtz result type
typedef __attribute__((ext_vector_type(8))) _Float16 f16x8;    // MFMA operand type
typedef __attribute__((ext_vector_type(4))) float    f32x4;

typedef union { uint4 q; f16x8 v; } BFrag;
typedef union { fp16x2 h[4]; f16x8 v; } AFrag;
typedef union { fp16x2 h[2]; uint2 u; } Pack4;

struct Stage {
    float a[8];
    uint4 b[3];
};

// sorted(set(row))[:2] -> (e0, e1, mask). mask=0 when only one unique module.
__device__ __forceinline__ void route(const int* pw, bool is64, int row,
                                      int& e0, int& e1, float& m) {
    int v0, v1, v2;
    if (is64) {
        v0 = pw[(row * 3 + 0) * 2];
        v1 = pw[(row * 3 + 1) * 2];
        v2 = pw[(row * 3 + 2) * 2];
    } else {
        v0 = pw[row * 3 + 0];
        v1 = pw[row * 3 + 1];
        v2 = pw[row * 3 + 2];
    }
    int lo  = min(v0, min(v1, v2));
    int hi  = max(v0, max(v1, v2));
    int mid = v0 + v1 + v2 - lo - hi;
    e0 = lo;
    if (mid != lo)     { e1 = mid; m = 1.0f; }
    else if (hi != lo) { e1 = hi;  m = 1.0f; }
    else               { e1 = lo;  m = 0.0f; }
}

// gather the 4 per-lane 5-slices into a full 20-vector (static indexing)
__device__ __forceinline__ void gather20(const float my5[5], int ksub,
                                         float outv[HDIM]) {
    float r1[5];
#pragma unroll
    for (int j = 0; j < 5; ++j) r1[j] = __shfl_xor(my5[j], 1, 64);
    const bool b0 = (ksub & 1);
    float q[10];
#pragma unroll
    for (int j = 0; j < 5; ++j) {
        q[j]     = b0 ? r1[j]  : my5[j];
        q[5 + j] = b0 ? my5[j] : r1[j];
    }
    float r2[10];
#pragma unroll
    for (int j = 0; j < 10; ++j) r2[j] = __shfl_xor(q[j], 2, 64);
    const bool b1 = (ksub & 2);
#pragma unroll
    for (int j = 0; j < 10; ++j) {
        outv[j]      = b1 ? r2[j] : q[j];
        outv[10 + j] = b1 ? q[j]  : r2[j];
    }
}

// ---- pre-kernel: W1 (fp32) -> fp16, same [e][o][k] layout ----
__global__ __launch_bounds__(256)
void cvt_w1_kernel(const float* __restrict__ W1, _Float16* __restrict__ Wh) {
    const int i = (blockIdx.x * 256 + threadIdx.x) * 4;
    if (i < W1ELEMS) {
        const float4 v = *reinterpret_cast<const float4*>(W1 + i);
        Pack4 pk;
        pk.h[0] = __builtin_amdgcn_cvt_pkrtz(v.x, v.y);
        pk.h[1] = __builtin_amdgcn_cvt_pkrtz(v.z, v.w);
        *reinterpret_cast<uint2*>(Wh + i) = pk.u;
    }
}

// stage loads for step i (compile-time constant after unroll)
__device__ __forceinline__ void loadStage(int i, int kg,
                                          const float* __restrict__ aptr,
                                          const _Float16* const bptr[3],
                                          Stage& st) {
    const bool full = (i < NFULL);
    if (full || kg < 2) {
        const int k0 = i * 32;
        const float4 q0 = *reinterpret_cast<const float4*>(aptr + k0);
        const float4 q1 = *reinterpret_cast<const float4*>(aptr + k0 + 4);
        st.a[0] = q0.x; st.a[1] = q0.y; st.a[2] = q0.z; st.a[3] = q0.w;
        st.a[4] = q1.x; st.a[5] = q1.y; st.a[6] = q1.z; st.a[7] = q1.w;
#pragma unroll
        for (int tt = 0; tt < 3; ++tt)
            st.b[tt] = *reinterpret_cast<const uint4*>(bptr[tt] + k0);
    } else {
#pragma unroll
        for (int j = 0; j < 8; ++j) st.a[j] = 0.0f;
#pragma unroll
        for (int tt = 0; tt < 3; ++tt)
            st.b[tt] = make_uint4(0, 0, 0, 0);
    }
}

__device__ __forceinline__ void computeStep(const Stage& st, f32x4 acc[3]) {
    AFrag a;
#pragma unroll
    for (int j = 0; j < 4; ++j)
        a.h[j] = __builtin_amdgcn_cvt_pkrtz(st.a[2 * j], st.a[2 * j + 1]);
#pragma unroll
    for (int tt = 0; tt < 3; ++tt) {
        BFrag b;
        b.q = st.b[tt];
        acc[tt] = __builtin_amdgcn_mfma_f32_16x16x32_f16(a.v, b.v, acc[tt], 0, 0, 0);
    }
}

__global__ __launch_bounds__(THREADS, 4)
void pathnet_kernel(const float* __restrict__ x,
                    const _Float16* __restrict__ Wh, const float* __restrict__ b1,
                    const float* __restrict__ W2, const float* __restrict__ b2,
                    const float* __restrict__ W3, const float* __restrict__ b3,
                    const float* __restrict__ Wl, const float* __restrict__ bl,
                    const int*   __restrict__ pathway,
                    float* __restrict__ out)
{
    __shared__ float preLds[4][SPW][PSTRIDE];   // 12.25 KB

    const int t    = threadIdx.x;
    const int lane = t & 63;
    const int w    = __builtin_amdgcn_readfirstlane(t >> 6);

    // ---- routing (uniform) ----
    bool is64 = ((pathway[1] | pathway[3] | pathway[5] | pathway[7]) == 0);
    int e10, e11, e20, e21, e30, e31;
    float m1, m2, m3;
    route(pathway, is64, 0, e10, e11, m1);
    route(pathway, is64, 1, e20, e21, m2);
    route(pathway, is64, 2, e30, e31, m3);
    e10 = __builtin_amdgcn_readfirstlane(e10);
    e11 = __builtin_amdgcn_readfirstlane(e11);
    e20 = __builtin_amdgcn_readfirstlane(e20);
    e21 = __builtin_amdgcn_readfirstlane(e21);
    e30 = __builtin_amdgcn_readfirstlane(e30);
    e31 = __builtin_amdgcn_readfirstlane(e31);

    // ---- layer 1 as MFMA GEMM: C[16 samples][48 units] per wave ----
    const int row = lane & 15;            // A row / B col within tile
    const int kg  = lane >> 4;            // k-group (8 elems each)
    const int sbase = blockIdx.x * SPB + w * SPW;

    const float* aptr = x + (size_t)(sbase + row) * IN_DIM + kg * 8;

    const _Float16* bptr[3];
#pragma unroll
    for (int tt = 0; tt < 3; ++tt) {
        int u = tt * 16 + row;            // unit 0..47
        int e, o;
        if (u < HDIM)          { e = e10; o = u; }
        else if (u < 2 * HDIM) { e = e11; o = u - HDIM; }
        else                   { e = e10; o = 0; }   // pad cols: safe garbage
        bptr[tt] = Wh + ((size_t)e * HDIM + o) * IN_DIM + kg * 8;
    }

    f32x4 acc[3];
#pragma unroll
    for (int tt = 0; tt < 3; ++tt) acc[tt] = (f32x4){0.f, 0.f, 0.f, 0.f};

    // ---- depth-3 software pipeline over 25 steps ----
    Stage st[3];
    loadStage(0, kg, aptr, bptr, st[0]);
    loadStage(1, kg, aptr, bptr, st[1]);
#pragma unroll
    for (int i = 0; i < NSTEPS; ++i) {
        if (i + 2 < NSTEPS) loadStage(i + 2, kg, aptr, bptr, st[(i + 2) % 3]);
        computeStep(st[i % 3], acc);
    }

    // ---- C frag -> LDS: col = lane&15 (+16*tile), row = (lane>>4)*4 + reg ----
#pragma unroll
    for (int tt = 0; tt < 3; ++tt) {
        const int col = tt * 16 + row;
        if (col < 2 * HDIM) {
#pragma unroll
            for (int r = 0; r < 4; ++r)
                preLds[w][kg * 4 + r][col] = acc[tt][r];
        }
    }
    __syncthreads();

    // ---- epilogue: 4 lanes per sample ----
    const int s    = lane >> 2;           // local sample 0..15
    const int ksub = lane & 3;

    float h1[HDIM];
#pragma unroll
    for (int c = 0; c < HDIM; ++c) {
        const float p0 = preLds[w][s][c];
        const float p1 = preLds[w][s][HDIM + c];
        h1[c] = fmaxf(p0 + b1[e10 * HDIM + c], 0.0f)
              + m1 * fmaxf(p1 + b1[e11 * HDIM + c], 0.0f);
    }

    float my5[5];
#pragma unroll
    for (int j = 0; j < 5; ++j) {
        const int o = ksub * 5 + j;
        float a0 = b2[e20 * HDIM + o];
        float a1 = b2[e21 * HDIM + o];
        const float* r0 = W2 + ((size_t)e20 * HDIM + o) * HDIM;
        const float* r1 = W2 + ((size_t)e21 * HDIM + o) * HDIM;
#pragma unroll
        for (int c = 0; c < HDIM; ++c) {
            a0 += h1[c] * r0[c];
            a1 += h1[c] * r1[c];
        }
        my5[j] = fmaxf(a0, 0.0f) + m2 * fmaxf(a1, 0.0f);
    }
    float h2[HDIM];
    gather20(my5, ksub, h2);

#pragma unroll
    for (int j = 0; j < 5; ++j) {
        const int o = ksub * 5 + j;
        float a0 = b3[e30 * HDIM + o];
        float a1 = b3[e31 * HDIM + o];
        const float* r0 = W3 + ((size_t)e30 * HDIM + o) * HDIM;
        const float* r1 = W3 + ((size_t)e31 * HDIM + o) * HDIM;
#pragma unroll
        for (int c = 0; c < HDIM; ++c) {
            a0 += h2[c] * r0[c];
            a1 += h2[c] * r1[c];
        }
        my5[j] = fmaxf(a0, 0.0f) + m3 * fmaxf(a1, 0.0f);
    }
    float h3[HDIM];
    gather20(my5, ksub, h3);

    const int srow = sbase + s;
    const int c0 = ksub * 2;
    float ya = bl[c0], yb = bl[c0 + 1];
    const float* wr0 = Wl + c0 * HDIM;
    const float* wr1 = Wl + (c0 + 1) * HDIM;
#pragma unroll
    for (int o = 0; o < HDIM; ++o) {
        ya += h3[o] * wr0[o];
        yb += h3[o] * wr1[o];
    }
    float* op = out + (size_t)srow * NCLS;
    *reinterpret_cast<float2*>(op + c0) = make_float2(ya, yb);

    if (ksub == 0) {
        float y8 = bl[8], y9 = bl[9];
        const float* w8 = Wl + 8 * HDIM;
        const float* w9 = Wl + 9 * HDIM;
#pragma unroll
        for (int o = 0; o < HDIM; ++o) {
            y8 += h3[o] * w8[o];
            y9 += h3[o] * w9[o];
        }
        *reinterpret_cast<float2*>(op + 8) = make_float2(y8, y9);
    }
}

extern "C" void kernel_launch(void* const* d_in, const int* in_sizes, int n_in,
                              void* d_out, int out_size, void* d_ws, size_t ws_size,
                              hipStream_t stream) {
    const float* x  = (const float*)d_in[0];
    const float* W1 = (const float*)d_in[1];
    const float* b1 = (const float*)d_in[2];
    const float* W2 = (const float*)d_in[3];
    const float* b2 = (const float*)d_in[4];
    const float* W3 = (const float*)d_in[5];
    const float* b3 = (const float*)d_in[6];
    const float* Wl = (const float*)d_in[7];
    const float* bl = (const float*)d_in[8];
    const int*   pw = (const int*)d_in[9];
    float* out = (float*)d_out;

    _Float16* Wh = (_Float16*)d_ws;      // 313.6 KB of scratch

    cvt_w1_kernel<<<(W1ELEMS / 4 + 255) / 256, 256, 0, stream>>>(W1, Wh);

    dim3 grid(BATCH / SPB);   // 1024 blocks x 4 waves
    pathnet_kernel<<<grid, THREADS, 0, stream>>>(x, Wh, b1, W2, b2,
                                                 W3, b3, Wl, bl, pw, out);
}